// Round 1
// baseline (1018.461 us; speedup 1.0000x reference)
//
#include <hip/hip_runtime.h>
#include <hip/hip_bf16.h>

// Problem constants
// b=2, n=4096, d=128, K=32, ein=257, hidden=514, cf=16, node_in=144, node_h=256
#define NNODES 8192      // b*n
#define NPTS   4096      // n per batch
#define KNN    32
#define EH     514       // edge hidden
#define EH2    1028      // A|B concat
#define CF     16
#define NDIN   144
#define NDH    256
#define DD     128

__device__ __forceinline__ float gelu_f(float v) {
    return 0.5f * v * (1.0f + erff(v * 0.70710678118654752440f));
}

// ---------------- repack: Wcat[1028][128], biascat[1028], w3[514] ----------------
__global__ __launch_bounds__(256) void repack_kernel(
    const float* __restrict__ We1, const float* __restrict__ be1,
    float* __restrict__ Wcat, float* __restrict__ biascat, float* __restrict__ w3buf)
{
    int tid = blockIdx.x * 256 + threadIdx.x;
    if (tid < EH2 * DD) {
        int nn = tid >> 7, kk = tid & 127;
        Wcat[tid] = (nn < EH) ? We1[nn * 257 + kk] : We1[(nn - EH) * 257 + 128 + kk];
    }
    if (tid < EH2) biascat[tid] = (tid < EH) ? be1[tid] : 0.0f;
    if (tid < EH)  w3buf[tid] = We1[tid * 257 + 256];
}

// ---------------- generic tiled f32 GEMM: C = act(A@B^T + bias) (+res) ----------------
// A[M,K] lda, B[N,K] ldb (weight layout [out,in]), bias[N] or null, res[M,ldr] or null
#define BM 64
#define BN 64
#define BKK 16
template <int ACT, int RES>
__global__ __launch_bounds__(256) void gemm_kernel(
    const float* __restrict__ A, int lda,
    const float* __restrict__ B, int ldb,
    const float* __restrict__ bias,
    const float* __restrict__ res, int ldr,
    float* __restrict__ C, int ldc,
    int M, int N, int K)
{
    __shared__ float As[BKK][BM + 1];
    __shared__ float Bs[BKK][BN + 1];
    int tid = threadIdx.x;
    int tx = tid & 15, ty = tid >> 4;
    int bm = blockIdx.x * BM, bn = blockIdx.y * BN;
    float acc[4][4] = {};
    for (int k0 = 0; k0 < K; k0 += BKK) {
#pragma unroll
        for (int r = 0; r < 4; ++r) {
            int idx = tid + r * 256;
            int m = idx >> 4, kk = idx & 15;
            As[kk][m] = A[(size_t)(bm + m) * lda + k0 + kk];
            Bs[kk][m] = (bn + m < N) ? B[(size_t)(bn + m) * ldb + k0 + kk] : 0.0f;
        }
        __syncthreads();
#pragma unroll
        for (int kk = 0; kk < BKK; ++kk) {
            float a[4], bb[4];
#pragma unroll
            for (int i = 0; i < 4; ++i) a[i] = As[kk][ty * 4 + i];
#pragma unroll
            for (int j = 0; j < 4; ++j) bb[j] = Bs[kk][tx * 4 + j];
#pragma unroll
            for (int i = 0; i < 4; ++i)
#pragma unroll
                for (int j = 0; j < 4; ++j) acc[i][j] += a[i] * bb[j];
        }
        __syncthreads();
    }
#pragma unroll
    for (int i = 0; i < 4; ++i) {
        int m = bm + ty * 4 + i;
#pragma unroll
        for (int j = 0; j < 4; ++j) {
            int n = bn + tx * 4 + j;
            if (n < N) {
                float v = acc[i][j];
                if (bias) v += bias[n];
                if (ACT == 1) v = gelu_f(v);
                if (RES) v += res[(size_t)m * ldr + n];
                C[(size_t)m * ldc + n] = v;
            }
        }
    }
}

// ---------------- KNN: one block per node, 32 smallest (dist, idx) ----------------
__global__ __launch_bounds__(256) void knn_kernel(
    const float* __restrict__ x, int* __restrict__ kidx, float* __restrict__ kdist)
{
    int node = blockIdx.x;
    int b = node >> 12, i = node & 4095;
    const float* xb = x + (size_t)b * NPTS * 3;
    float xi0 = xb[i * 3 + 0], xi1 = xb[i * 3 + 1], xi2 = xb[i * 3 + 2];
    int tid = threadIdx.x;
    unsigned long long keys[16];
    unsigned long long lmin = ~0ull;
#pragma unroll
    for (int c = 0; c < 16; ++c) {
        int j = tid + (c << 8);
        float dx = xi0 - xb[j * 3 + 0];
        float dy = xi1 - xb[j * 3 + 1];
        float dz = xi2 - xb[j * 3 + 2];
        float d = dx * dx + dy * dy + dz * dz;
        unsigned long long key = ((unsigned long long)__float_as_uint(d) << 32) | (unsigned)j;
        keys[c] = key;
        lmin = (key < lmin) ? key : lmin;
    }
    __shared__ unsigned long long wmin[4];
    __shared__ unsigned long long winner;
    int lane = tid & 63, wv = tid >> 6;
    for (int t = 0; t < KNN; ++t) {
        unsigned long long m = lmin;
#pragma unroll
        for (int off = 32; off; off >>= 1) {
            unsigned long long o = __shfl_down(m, off);
            m = (o < m) ? o : m;
        }
        if (lane == 0) wmin[wv] = m;
        __syncthreads();
        if (tid == 0) {
            unsigned long long w = wmin[0];
#pragma unroll
            for (int q = 1; q < 4; ++q) w = (wmin[q] < w) ? wmin[q] : w;
            winner = w;
            kidx[node * KNN + t] = (int)(unsigned)(w & 0xffffffffull);
            kdist[node * KNN + t] = __uint_as_float((unsigned)(w >> 32));
        }
        __syncthreads();
        unsigned long long w = winner;
        if (lmin == w) {  // unique owner (keys contain unique j)
            unsigned long long nm = ~0ull;
#pragma unroll
            for (int c = 0; c < 16; ++c) {
                if (keys[c] == w) keys[c] = ~0ull;
                nm = (keys[c] < nm) ? keys[c] : nm;
            }
            lmin = nm;
        }
        __syncthreads();
    }
}

// ---------------- edge kernel: combine + gelu + layer2 + gelu + sum over k ----------------
// Writes node_in[node][0:128]=h, [128:144]=m_i
#define W2S 520  // padded LDS stride for We2
__global__ __launch_bounds__(256) void edge_kernel(
    const float* __restrict__ AB, const float* __restrict__ w3buf,
    const float* __restrict__ We2, const float* __restrict__ be2,
    const float* __restrict__ h,
    const int* __restrict__ kidx, const float* __restrict__ kdist,
    float* __restrict__ nodein)
{
    __shared__ float sA[EH];
    __shared__ float sw3[EH];
    __shared__ float sv[EH];
    __shared__ float sW2[CF * W2S];
    int node = blockIdx.x;
    int b = node >> 12;
    int tid = threadIdx.x;
    const float* Arow = AB + (size_t)node * EH2;
    for (int o = tid; o < EH; o += 256) { sA[o] = Arow[o]; sw3[o] = w3buf[o]; }
    for (int idx = tid; idx < CF * EH; idx += 256) {
        int c = idx / EH, o = idx - c * EH;
        sW2[c * W2S + o] = We2[idx];
    }
    if (tid < DD) nodein[(size_t)node * NDIN + tid] = h[(size_t)node * DD + tid];
    __syncthreads();
    int c = tid >> 4, l = tid & 15;
    float acc = 0.0f;
    for (int k = 0; k < KNN; ++k) {
        int j = kidx[node * KNN + k];
        float d = kdist[node * KNN + k];
        const float* Bj = AB + (size_t)((b << 12) + j) * EH2 + EH;
        for (int o = tid; o < EH; o += 256) {
            float v = sA[o] + Bj[o] + sw3[o] * d;
            sv[o] = gelu_f(v);
        }
        __syncthreads();
        float p = 0.0f;
        for (int o = l; o < EH; o += 16) p += sv[o] * sW2[c * W2S + o];
        p += __shfl_xor(p, 8);
        p += __shfl_xor(p, 4);
        p += __shfl_xor(p, 2);
        p += __shfl_xor(p, 1);
        if (l == 0) acc += gelu_f(p + be2[c]);
        __syncthreads();
    }
    if (l == 0) nodein[(size_t)node * NDIN + DD + c] = acc;
}

extern "C" void kernel_launch(void* const* d_in, const int* in_sizes, int n_in,
                              void* d_out, int out_size, void* d_ws, size_t ws_size,
                              hipStream_t stream) {
    const float* h   = (const float*)d_in[0];
    const float* x   = (const float*)d_in[1];
    const float* We1 = (const float*)d_in[2];
    const float* be1 = (const float*)d_in[3];
    const float* We2 = (const float*)d_in[4];
    const float* be2 = (const float*)d_in[5];
    const float* Wn1 = (const float*)d_in[6];
    const float* bn1 = (const float*)d_in[7];
    const float* Wn2 = (const float*)d_in[8];
    const float* bn2 = (const float*)d_in[9];
    float* out = (float*)d_out;

    char* ws = (char*)d_ws;
    size_t off = 0;
    auto alloc = [&](size_t bytes) -> void* {
        void* p = ws + off;
        off = (off + bytes + 255) & ~(size_t)255;
        return p;
    };
    float* Wcat    = (float*)alloc((size_t)EH2 * DD * 4);
    float* biascat = (float*)alloc((size_t)EH2 * 4);
    float* w3buf   = (float*)alloc((size_t)EH * 4);
    float* AB      = (float*)alloc((size_t)NNODES * EH2 * 4);
    int*   kidx    = (int*)alloc((size_t)NNODES * KNN * 4);
    float* kdist   = (float*)alloc((size_t)NNODES * KNN * 4);
    float* nodein  = (float*)alloc((size_t)NNODES * NDIN * 4);
    float* hid     = (float*)alloc((size_t)NNODES * NDH * 4);

    // 1. repack weights
    repack_kernel<<<(EH2 * DD + 255) / 256, 256, 0, stream>>>(We1, be1, Wcat, biascat, w3buf);
    // 2. AB = h @ Wcat^T + biascat   [8192 x 1028]
    gemm_kernel<0, 0><<<dim3(NNODES / BM, (EH2 + BN - 1) / BN), 256, 0, stream>>>(
        h, DD, Wcat, DD, biascat, nullptr, 0, AB, EH2, NNODES, EH2, DD);
    // 3. KNN
    knn_kernel<<<NNODES, 256, 0, stream>>>(x, kidx, kdist);
    // 4. edge MLP + aggregate -> nodein
    edge_kernel<<<NNODES, 256, 0, stream>>>(AB, w3buf, We2, be2, h, kidx, kdist, nodein);
    // 5. hid = gelu(nodein @ Wn1^T + bn1)  [8192 x 256]
    gemm_kernel<1, 0><<<dim3(NNODES / BM, NDH / BN), 256, 0, stream>>>(
        nodein, NDIN, Wn1, NDIN, bn1, nullptr, 0, hid, NDH, NNODES, NDH, NDIN);
    // 6. out = hid @ Wn2^T + bn2 + h  [8192 x 128]
    gemm_kernel<0, 1><<<dim3(NNODES / BM, DD / BN), 256, 0, stream>>>(
        hid, NDH, Wn2, NDH, bn2, h, DD, out, DD, NNODES, DD, NDH);
}

// Round 2
// 383.191 us; speedup vs baseline: 2.6578x; 2.6578x over previous
//
#include <hip/hip_runtime.h>
#include <hip/hip_bf16.h>

// b=2, n=4096, d=128, K=32, ein=257, hidden=514, cf=16, node_in=144, node_h=256
#define NNODES 8192
#define NPTS   4096
#define KNN    32
#define EH     514
#define EH2    1028
#define CF     16
#define NDIN   144
#define NDH    256
#define DD     128
#define RS     520          // f32 row stride for A/B halves
#define PS     552          // ushort row stride for P tile (bank spread)
#define NKB    17           // K blocks of 32 (544 padded)

typedef __attribute__((ext_vector_type(8))) short short8;
typedef __attribute__((ext_vector_type(4))) float f32x4;
typedef __attribute__((ext_vector_type(4))) unsigned short ushort4v;

__device__ __forceinline__ float fast_gelu(float v) {
    // v * sigmoid(1.702 v); |err| vs exact erf-gelu < 0.021 abs, ~1e-4 at our tiny v
    float t = __expf(-1.702f * v);
    return v * __builtin_amdgcn_rcpf(1.0f + t);
}

__device__ __forceinline__ unsigned short bf16rne(float f) {
    unsigned u = __float_as_uint(f);
    u += 0x7fffu + ((u >> 16) & 1u);
    return (unsigned short)(u >> 16);
}

// ---------------- repack: Wcat[1028][128], biascat, w3, W2f frag layout ----------------
__global__ __launch_bounds__(256) void repack_kernel(
    const float* __restrict__ We1, const float* __restrict__ be1,
    const float* __restrict__ We2,
    float* __restrict__ Wcat, float* __restrict__ biascat, float* __restrict__ w3buf,
    unsigned short* __restrict__ W2f)
{
    int tid = blockIdx.x * 256 + threadIdx.x;
    if (tid < EH2 * DD) {
        int nn = tid >> 7, kk = tid & 127;
        Wcat[tid] = (nn < EH) ? We1[nn * 257 + kk] : We1[(nn - EH) * 257 + 128 + kk];
    }
    if (tid < EH2) biascat[tid] = (tid < EH) ? be1[tid] : 0.0f;
    if (tid < EH)  w3buf[tid] = We1[tid * 257 + 256];
    // W2f[kb][lane][i] = We2[c= lane&15][k = kb*32 + (lane>>4)*8 + i]  (0 pad for k>=514)
    if (tid < NKB * 64 * 8) {
        int kb = tid >> 9, l = (tid >> 3) & 63, i = tid & 7;
        int k = kb * 32 + ((l >> 4) << 3) + i;
        int c = l & 15;
        float v = (k < EH) ? We2[c * EH + k] : 0.0f;
        W2f[tid] = bf16rne(v);
    }
}

// ---------------- generic tiled f32 GEMM: C = act(A@B^T + bias) (+res) ----------------
#define BM 64
#define BN 64
#define BKK 16
template <int ACT, int RES, int SPLIT>
__global__ __launch_bounds__(256) void gemm_kernel(
    const float* __restrict__ A, int lda,
    const float* __restrict__ B, int ldb,
    const float* __restrict__ bias,
    const float* __restrict__ res, int ldr,
    float* __restrict__ C, int ldc,
    int M, int N, int K)
{
    __shared__ float As[BKK][BM + 1];
    __shared__ float Bs[BKK][BN + 1];
    int tid = threadIdx.x;
    int tx = tid & 15, ty = tid >> 4;
    int bm = blockIdx.x * BM, bn = blockIdx.y * BN;
    float acc[4][4] = {};
    for (int k0 = 0; k0 < K; k0 += BKK) {
#pragma unroll
        for (int r = 0; r < 4; ++r) {
            int idx = tid + r * 256;
            int m = idx >> 4, kk = idx & 15;
            As[kk][m] = A[(size_t)(bm + m) * lda + k0 + kk];
            Bs[kk][m] = (bn + m < N) ? B[(size_t)(bn + m) * ldb + k0 + kk] : 0.0f;
        }
        __syncthreads();
#pragma unroll
        for (int kk = 0; kk < BKK; ++kk) {
            float a[4], bb[4];
#pragma unroll
            for (int i = 0; i < 4; ++i) a[i] = As[kk][ty * 4 + i];
#pragma unroll
            for (int j = 0; j < 4; ++j) bb[j] = Bs[kk][tx * 4 + j];
#pragma unroll
            for (int i = 0; i < 4; ++i)
#pragma unroll
                for (int j = 0; j < 4; ++j) acc[i][j] += a[i] * bb[j];
        }
        __syncthreads();
    }
#pragma unroll
    for (int i = 0; i < 4; ++i) {
        int m = bm + ty * 4 + i;
#pragma unroll
        for (int j = 0; j < 4; ++j) {
            int n = bn + tx * 4 + j;
            if (n < N) {
                float v = acc[i][j];
                if (bias) v += bias[n];
                if (ACT == 1) v = fast_gelu(v);
                if (RES) v += res[(size_t)m * ldr + n];
                if (SPLIT) {
                    // n<514 -> Abuf[m][n]; else Bbuf[m][n-514]; rows stride RS
                    size_t boff = (n < EH) ? 0 : (size_t)NNODES * RS;
                    int col = (n < EH) ? n : n - EH;
                    C[boff + (size_t)m * RS + col] = v;
                } else {
                    C[(size_t)m * ldc + n] = v;
                }
            }
        }
    }
}

// ---------------- KNN: one block per node, 32 smallest (dist, idx) ----------------
__global__ __launch_bounds__(256) void knn_kernel(
    const float* __restrict__ x, int* __restrict__ kidx, float* __restrict__ kdist)
{
    int node = blockIdx.x;
    int b = node >> 12, i = node & 4095;
    const float* xb = x + (size_t)b * NPTS * 3;
    float xi0 = xb[i * 3 + 0], xi1 = xb[i * 3 + 1], xi2 = xb[i * 3 + 2];
    int tid = threadIdx.x;
    unsigned long long keys[16];
    unsigned long long lmin = ~0ull;
#pragma unroll
    for (int c = 0; c < 16; ++c) {
        int j = tid + (c << 8);
        float dx = xi0 - xb[j * 3 + 0];
        float dy = xi1 - xb[j * 3 + 1];
        float dz = xi2 - xb[j * 3 + 2];
        float d = dx * dx + dy * dy + dz * dz;
        unsigned long long key = ((unsigned long long)__float_as_uint(d) << 32) | (unsigned)j;
        keys[c] = key;
        lmin = (key < lmin) ? key : lmin;
    }
    __shared__ unsigned long long wmin[4];
    __shared__ unsigned long long winner;
    int lane = tid & 63, wv = tid >> 6;
    for (int t = 0; t < KNN; ++t) {
        unsigned long long m = lmin;
#pragma unroll
        for (int off = 32; off; off >>= 1) {
            unsigned long long o = __shfl_down(m, off);
            m = (o < m) ? o : m;
        }
        if (lane == 0) wmin[wv] = m;
        __syncthreads();
        if (tid == 0) {
            unsigned long long w = wmin[0];
#pragma unroll
            for (int q = 1; q < 4; ++q) w = (wmin[q] < w) ? wmin[q] : w;
            winner = w;
            kidx[node * KNN + t] = (int)(unsigned)(w & 0xffffffffull);
            kdist[node * KNN + t] = __uint_as_float((unsigned)(w >> 32));
        }
        __syncthreads();
        unsigned long long w = winner;
        if (lmin == w) {
            unsigned long long nm = ~0ull;
#pragma unroll
            for (int c = 0; c < 16; ++c) {
                if (keys[c] == w) keys[c] = ~0ull;
                nm = (keys[c] < nm) ? keys[c] : nm;
            }
            lmin = nm;
        }
        __syncthreads();
    }
}

// ---------------- edge kernel v2: combine -> bf16 P tile -> MFMA layer2 ----------------
__global__ __launch_bounds__(256) void edge_kernel(
    const float* __restrict__ Abuf, const float* __restrict__ w3buf,
    const unsigned short* __restrict__ W2f, const float* __restrict__ be2,
    const float* __restrict__ h,
    const int* __restrict__ kidx, const float* __restrict__ kdist,
    float* __restrict__ nodein)
{
    __shared__ unsigned short P[KNN * PS];          // 35328 B
    __shared__ float sA[RS];                         // 2080 B
    __shared__ float sw3[RS];                        // 2080 B
    __shared__ float accbuf[4][64][4];               // 4096 B
    __shared__ int   kjs[KNN];
    __shared__ float kds[KNN];

    int node = blockIdx.x;
    int bbase = (node >> 12) << 12;
    int tid = threadIdx.x;
    int wv = tid >> 6, lane = tid & 63;
    const float* Bbuf = Abuf + (size_t)NNODES * RS;

    // --- per-wave B-fragments from global (latency-hidden by init phase) ---
    int tile = wv & 1;
    int kb0 = (wv < 2) ? 0 : 9;
    int nkb = (wv < 2) ? 9 : 8;
    short8 bfr[9];
#pragma unroll
    for (int q = 0; q < 9; ++q) {
        if (q < nkb) {
            bfr[q] = *(const short8*)&W2f[((kb0 + q) * 64 + lane) * 8];
        }
    }

    // --- init: stage A row, w3, knn lists; zero P pad cols; copy h ---
    const float* Arow = Abuf + (size_t)node * RS;
    for (int o = tid; o < RS; o += 256) {
        sA[o] = (o < EH) ? Arow[o] : 0.0f;
        sw3[o] = (o < EH) ? w3buf[o] : 0.0f;
    }
    if (tid < KNN) {
        kjs[tid] = kidx[node * KNN + tid];
        kds[tid] = kdist[node * KNN + tid];
    }
    for (int idx = tid; idx < KNN * 24; idx += 256) {   // zero cols 520..543
        int r = idx / 24, c = idx - r * 24;
        P[r * PS + 520 + c] = 0;
    }
    if (tid < DD) nodein[(size_t)node * NDIN + tid] = h[(size_t)node * DD + tid];
    __syncthreads();

    // --- combine: P[e][o] = bf16(gelu(A_i[o] + B_j[o] + w3[o]*d)) ---
    {
        int e = tid >> 3, s = tid & 7;
        int jg = bbase + kjs[e];
        float dist = kds[e];
        const float4* Bj = (const float4*)(Bbuf + (size_t)jg * RS);
        const float4* A4 = (const float4*)sA;
        const float4* W4 = (const float4*)sw3;
        unsigned short* Pe = &P[e * PS];
#pragma unroll
        for (int i = 0; i < 17; ++i) {
            int chunk = s + (i << 3);
            if (chunk < 130) {
                float4 a = A4[chunk];
                float4 w = W4[chunk];
                float4 bj = Bj[chunk];
                float v0 = a.x + bj.x + w.x * dist;
                float v1 = a.y + bj.y + w.y * dist;
                float v2 = a.z + bj.z + w.z * dist;
                float v3 = a.w + bj.w + w.w * dist;
                ushort4v g;
                g.x = bf16rne(fast_gelu(v0));
                g.y = bf16rne(fast_gelu(v1));
                g.z = bf16rne(fast_gelu(v2));
                g.w = bf16rne(fast_gelu(v3));
                *(ushort4v*)&Pe[chunk << 2] = g;
            }
        }
    }
    __syncthreads();

    // --- layer 2: per-wave MFMA over its kb range / tile ---
    f32x4 acc = {0.0f, 0.0f, 0.0f, 0.0f};
    {
        int row = tile * 16 + (lane & 15);
        const unsigned short* Pb = &P[row * PS + ((lane >> 4) << 3)];
#pragma unroll
        for (int q = 0; q < 9; ++q) {
            if (q < nkb) {
                short8 a = *(const short8*)&Pb[(kb0 + q) * 32];
                acc = __builtin_amdgcn_mfma_f32_16x16x32_bf16(a, bfr[q], acc, 0, 0, 0);
            }
        }
    }
#pragma unroll
    for (int i = 0; i < 4; ++i) accbuf[wv][lane][i] = acc[i];
    __syncthreads();

    // --- epilogue: gelu per edge-output, sum over 32 edges, write m_i ---
    if (wv == 0) {
        float bias = be2[lane & 15];
        float p = 0.0f;
#pragma unroll
        for (int t = 0; t < 2; ++t) {
#pragma unroll
            for (int i = 0; i < 4; ++i) {
                float dv = accbuf[t][lane][i] + accbuf[t + 2][lane][i];
                p += fast_gelu(dv + bias);
            }
        }
        p += __shfl_xor(p, 16);
        p += __shfl_xor(p, 32);
        if (lane < CF) nodein[(size_t)node * NDIN + DD + lane] = p;
    }
}

extern "C" void kernel_launch(void* const* d_in, const int* in_sizes, int n_in,
                              void* d_out, int out_size, void* d_ws, size_t ws_size,
                              hipStream_t stream) {
    const float* h   = (const float*)d_in[0];
    const float* x   = (const float*)d_in[1];
    const float* We1 = (const float*)d_in[2];
    const float* be1 = (const float*)d_in[3];
    const float* We2 = (const float*)d_in[4];
    const float* be2 = (const float*)d_in[5];
    const float* Wn1 = (const float*)d_in[6];
    const float* bn1 = (const float*)d_in[7];
    const float* Wn2 = (const float*)d_in[8];
    const float* bn2 = (const float*)d_in[9];
    float* out = (float*)d_out;

    char* ws = (char*)d_ws;
    size_t off = 0;
    auto alloc = [&](size_t bytes) -> void* {
        void* p = ws + off;
        off = (off + bytes + 255) & ~(size_t)255;
        return p;
    };
    float* Wcat    = (float*)alloc((size_t)EH2 * DD * 4);
    float* biascat = (float*)alloc((size_t)EH2 * 4);
    float* w3buf   = (float*)alloc((size_t)EH * 4);
    unsigned short* W2f = (unsigned short*)alloc((size_t)NKB * 64 * 8 * 2);
    float* Abuf    = (float*)alloc((size_t)2 * NNODES * RS * 4);  // A half then B half
    int*   kidx    = (int*)alloc((size_t)NNODES * KNN * 4);
    float* kdist   = (float*)alloc((size_t)NNODES * KNN * 4);
    float* nodein  = (float*)alloc((size_t)NNODES * NDIN * 4);
    float* hid     = (float*)alloc((size_t)NNODES * NDH * 4);

    // 1. repack weights
    repack_kernel<<<(EH2 * DD + 255) / 256, 256, 0, stream>>>(
        We1, be1, We2, Wcat, biascat, w3buf, W2f);
    // 2. A|B = h @ Wcat^T + biascat  -> split buffers, row stride 520
    gemm_kernel<0, 0, 1><<<dim3(NNODES / BM, (EH2 + BN - 1) / BN), 256, 0, stream>>>(
        h, DD, Wcat, DD, biascat, nullptr, 0, Abuf, 0, NNODES, EH2, DD);
    // 3. KNN
    knn_kernel<<<NNODES, 256, 0, stream>>>(x, kidx, kdist);
    // 4. edge MLP + aggregate -> nodein
    edge_kernel<<<NNODES, 256, 0, stream>>>(Abuf, w3buf, W2f, be2, h, kidx, kdist, nodein);
    // 5. hid = gelu(nodein @ Wn1^T + bn1)
    gemm_kernel<1, 0, 0><<<dim3(NNODES / BM, NDH / BN), 256, 0, stream>>>(
        nodein, NDIN, Wn1, NDIN, bn1, nullptr, 0, hid, NDH, NNODES, NDH, NDIN);
    // 6. out = hid @ Wn2^T + bn2 + h
    gemm_kernel<0, 1, 0><<<dim3(NNODES / BM, DD / BN), 256, 0, stream>>>(
        hid, NDH, Wn2, NDH, bn2, h, DD, out, DD, NNODES, DD, NDH);
}

// Round 3
// 199.736 us; speedup vs baseline: 5.0990x; 1.9185x over previous
//
#include <hip/hip_runtime.h>
#include <hip/hip_bf16.h>

// b=2, n=4096, d=128, K=32, ein=257, hidden=514, cf=16, node_in=144, node_h=256
#define NNODES 8192
#define NPTS   4096
#define KNN    32
#define EH     514
#define EH2    1028
#define CF     16
#define DD     128
#define ABS    528          // ushort row stride for bf16 A/B halves (pad 514->528)
#define NPAD   1088         // gemm1 N padded to 17*64
#define PS     552          // ushort row stride for P tile
#define NKB    17           // K blocks of 32 (544 padded)
#define NDIN_P 160          // node_in 144 padded
#define NDH    256

typedef __attribute__((ext_vector_type(8))) short short8;
typedef __attribute__((ext_vector_type(8))) unsigned short u16x8;
typedef __attribute__((ext_vector_type(4))) float f32x4;

__device__ __forceinline__ float fast_gelu(float v) {
    float t = __expf(-1.702f * v);
    return v * __builtin_amdgcn_rcpf(1.0f + t);
}
__device__ __forceinline__ unsigned short bf16rne(float f) {
    unsigned u = __float_as_uint(f);
    u += 0x7fffu + ((u >> 16) & 1u);
    return (unsigned short)(u >> 16);
}
__device__ __forceinline__ float bf2f(unsigned short u) {
    return __uint_as_float((unsigned)u << 16);
}

// ---------------- repack: all weights -> bf16 layouts ----------------
// Wcatbf[1088][128] (rows>=1028 zero), biascat[1088] f32, w3buf[514] f32,
// W2f frag layout, Wn1bf[256][160] (cols>=144 zero), Wn2bf[128][256]
__global__ __launch_bounds__(256) void repack_kernel(
    const float* __restrict__ We1, const float* __restrict__ be1,
    const float* __restrict__ We2,
    const float* __restrict__ Wn1, const float* __restrict__ Wn2,
    unsigned short* __restrict__ Wcatbf, float* __restrict__ biascat,
    float* __restrict__ w3buf, unsigned short* __restrict__ W2f,
    unsigned short* __restrict__ Wn1bf, unsigned short* __restrict__ Wn2bf)
{
    int tid = blockIdx.x * 256 + threadIdx.x;
    if (tid < NPAD * DD) {
        int nn = tid >> 7, kk = tid & 127;
        float v = (nn < EH) ? We1[nn * 257 + kk]
                : (nn < EH2) ? We1[(nn - EH) * 257 + 128 + kk] : 0.0f;
        Wcatbf[tid] = bf16rne(v);
    }
    if (tid < NPAD) biascat[tid] = (tid < EH) ? be1[tid] : 0.0f;
    if (tid < EH)   w3buf[tid] = We1[tid * 257 + 256];
    if (tid < NKB * 64 * 8) {
        int kb = tid >> 9, l = (tid >> 3) & 63, i = tid & 7;
        int k = kb * 32 + ((l >> 4) << 3) + i;
        int c = l & 15;
        W2f[tid] = bf16rne((k < EH) ? We2[c * EH + k] : 0.0f);
    }
    if (tid < NDH * NDIN_P) {
        int r = tid / NDIN_P, c = tid - r * NDIN_P;
        Wn1bf[tid] = bf16rne((c < 144) ? Wn1[r * 144 + c] : 0.0f);
    }
    if (tid < DD * NDH) Wn2bf[tid] = bf16rne(Wn2[tid]);
}

// ---------------- h -> bf16 ----------------
__global__ __launch_bounds__(256) void hcast_kernel(
    const float* __restrict__ h, unsigned short* __restrict__ hbf)
{
    int idx = (blockIdx.x * 256 + threadIdx.x) * 4;
    float4 v = *(const float4*)&h[idx];
    unsigned short o0 = bf16rne(v.x), o1 = bf16rne(v.y), o2 = bf16rne(v.z), o3 = bf16rne(v.w);
    hbf[idx] = o0; hbf[idx + 1] = o1; hbf[idx + 2] = o2; hbf[idx + 3] = o3;
}

// ---------------- MFMA GEMM: C = act(A@B^T + bias) (+res), bf16 in, direct frags ----------------
// MS: m-subtiles per wave (BM = MS*64). Grid: (M/(MS*64), Npad/64).
template <int ACT, int RES, int SPLIT, int OUTBF, int MS>
__global__ __launch_bounds__(256) void mgemm_kernel(
    const unsigned short* __restrict__ A, int lda,
    const unsigned short* __restrict__ B, int ldb,
    const float* __restrict__ bias,
    const float* __restrict__ res, int ldr,
    void* __restrict__ Cv, int ldc,
    unsigned short* __restrict__ Csb,   // SPLIT: A-half base; B-half at +NNODES*ABS
    int Nreal, int ksteps)
{
    int tid = threadIdx.x;
    int wv = tid >> 6, l = tid & 63;
    int bm = blockIdx.x * (MS * 64);
    int bn = blockIdx.y * 64;
    int r = l & 15, ko = (l >> 4) << 3;
    f32x4 acc[MS][4] = {};
    const unsigned short* Ab0 = A + (size_t)(bm + wv * (MS * 16) + r) * lda + ko;
    const unsigned short* Bb0 = B + (size_t)(bn + r) * ldb + ko;
    for (int ks = 0; ks < ksteps; ++ks) {
        int kk = ks << 5;
        short8 av[MS];
#pragma unroll
        for (int m = 0; m < MS; ++m)
            av[m] = *(const short8*)(Ab0 + (size_t)(m * 16) * lda + kk);
        short8 bv[4];
#pragma unroll
        for (int j = 0; j < 4; ++j)
            bv[j] = *(const short8*)(Bb0 + (size_t)(j * 16) * ldb + kk);
#pragma unroll
        for (int m = 0; m < MS; ++m)
#pragma unroll
            for (int j = 0; j < 4; ++j)
                acc[m][j] = __builtin_amdgcn_mfma_f32_16x16x32_bf16(av[m], bv[j], acc[m][j], 0, 0, 0);
    }
#pragma unroll
    for (int m = 0; m < MS; ++m) {
#pragma unroll
        for (int j = 0; j < 4; ++j) {
            int col = bn + j * 16 + (l & 15);
            float bs = (col < Nreal) ? bias[col] : 0.0f;
#pragma unroll
            for (int i = 0; i < 4; ++i) {
                int row = bm + wv * (MS * 16) + m * 16 + ((l >> 4) << 2) + i;
                float v = acc[m][j][i] + bs;
                if (ACT) v = fast_gelu(v);
                if (SPLIT) {
                    // virtual col: <514 -> A-half; <1028 -> B-half; 1028..1041 -> zero B pad
                    if (col < EH) Csb[(size_t)row * ABS + col] = bf16rne(v);
                    else if (col < EH2) Csb[(size_t)NNODES * ABS + (size_t)row * ABS + (col - EH)] = bf16rne(v);
                    else if (col < EH2 + 14) Csb[(size_t)NNODES * ABS + (size_t)row * ABS + (col - EH)] = 0;
                } else if (col < Nreal) {
                    if (RES) v += res[(size_t)row * ldr + col];
                    if (OUTBF) ((unsigned short*)Cv)[(size_t)row * ldc + col] = bf16rne(v);
                    else       ((float*)Cv)[(size_t)row * ldc + col] = v;
                }
            }
        }
    }
}

// ---------------- KNN via two-level radix select ----------------
__global__ __launch_bounds__(256) void knn_kernel(
    const float* __restrict__ x, int* __restrict__ kidx, float* __restrict__ kdist)
{
    __shared__ unsigned hist[256];
    __shared__ unsigned long long L1[32];
    __shared__ unsigned long long L2[256];
    __shared__ int sb0, sc0, sb1, scb, scnt1, n1, n2;
    int node = blockIdx.x;
    int b = node >> 12, i = node & 4095;
    const float* xb = x + (size_t)b * NPTS * 3;
    float xi0 = xb[i * 3], xi1 = xb[i * 3 + 1], xi2 = xb[i * 3 + 2];
    int tid = threadIdx.x;
    int lane = tid & 63, wv = tid >> 6;
    unsigned keys[16];
#pragma unroll
    for (int c = 0; c < 16; ++c) {
        int j = (c << 8) + tid;
        float dx = xi0 - xb[j * 3], dy = xi1 - xb[j * 3 + 1], dz = xi2 - xb[j * 3 + 2];
        keys[c] = __float_as_uint(dx * dx + dy * dy + dz * dz);
    }
    hist[tid] = 0;
    __syncthreads();
#pragma unroll
    for (int c = 0; c < 16; ++c) atomicAdd(&hist[keys[c] >> 24], 1u);
    __syncthreads();
    if (wv == 0) {  // level-1 scan: find bin of 32nd smallest
        unsigned h0 = hist[lane * 4], h1 = hist[lane * 4 + 1],
                 h2 = hist[lane * 4 + 2], h3 = hist[lane * 4 + 3];
        unsigned s = h0 + h1 + h2 + h3, v = s;
        for (int off = 1; off < 64; off <<= 1) {
            unsigned o = __shfl_up(v, off);
            if (lane >= off) v += o;
        }
        unsigned e0 = v - s, e1 = e0 + h0, e2 = e1 + h1, e3 = e2 + h2;
        if (e0 < 32 && e0 + h0 >= 32) { sb0 = lane * 4;     sc0 = (int)e0; }
        if (e1 < 32 && e1 + h1 >= 32) { sb0 = lane * 4 + 1; sc0 = (int)e1; }
        if (e2 < 32 && e2 + h2 >= 32) { sb0 = lane * 4 + 2; sc0 = (int)e2; }
        if (e3 < 32 && e3 + h3 >= 32) { sb0 = lane * 4 + 3; sc0 = (int)e3; }
    }
    __syncthreads();
    int b0 = sb0, c0 = sc0;
    hist[tid] = 0;
    __syncthreads();
#pragma unroll
    for (int c = 0; c < 16; ++c)
        if ((keys[c] >> 24) == (unsigned)b0) atomicAdd(&hist[(keys[c] >> 16) & 0xFF], 1u);
    __syncthreads();
    if (wv == 0) {  // level-2 scan: target = 32 - c0 within bin b0
        int target = 32 - c0;
        unsigned h0 = hist[lane * 4], h1 = hist[lane * 4 + 1],
                 h2 = hist[lane * 4 + 2], h3 = hist[lane * 4 + 3];
        unsigned s = h0 + h1 + h2 + h3, v = s;
        for (int off = 1; off < 64; off <<= 1) {
            unsigned o = __shfl_up(v, off);
            if (lane >= off) v += o;
        }
        unsigned e0 = v - s, e1 = e0 + h0, e2 = e1 + h1, e3 = e2 + h2;
        if ((int)e0 < target && (int)(e0 + h0) >= target) { sb1 = lane * 4;     scb = c0 + (int)e0; scnt1 = (int)h0; }
        if ((int)e1 < target && (int)(e1 + h1) >= target) { sb1 = lane * 4 + 1; scb = c0 + (int)e1; scnt1 = (int)h1; }
        if ((int)e2 < target && (int)(e2 + h2) >= target) { sb1 = lane * 4 + 2; scb = c0 + (int)e2; scnt1 = (int)h2; }
        if ((int)e3 < target && (int)(e3 + h3) >= target) { sb1 = lane * 4 + 3; scb = c0 + (int)e3; scnt1 = (int)h3; }
    }
    if (tid == 64) { n1 = 0; n2 = 0; }
    __syncthreads();
    int b1 = sb1, cb = scb, cnt1 = scnt1;
    unsigned T = ((unsigned)b0 << 8) | (unsigned)b1;
#pragma unroll
    for (int c = 0; c < 16; ++c) {
        unsigned k16 = keys[c] >> 16;
        int j = (c << 8) + tid;
        unsigned long long pk = ((unsigned long long)keys[c] << 32) | (unsigned)j;
        if (k16 < T) {
            int p = atomicAdd(&n1, 1);
            L1[p] = pk;
        } else if (k16 == T) {
            int p = atomicAdd(&n2, 1);
            if (p < 256) L2[p] = pk;
        }
    }
    __syncthreads();
    int need = 32 - cb;
    int m2 = cnt1 < 256 ? cnt1 : 256;
    if (cnt1 == need) {
        if (tid < need) L1[cb + tid] = L2[tid];
    } else if (wv == 0) {
        unsigned long long v0[4];
#pragma unroll
        for (int q = 0; q < 4; ++q) {
            int idx = (q << 6) + lane;
            v0[q] = (idx < m2) ? L2[idx] : ~0ull;
        }
        for (int t = 0; t < need; ++t) {
            unsigned long long m = v0[0] < v0[1] ? v0[0] : v0[1];
            unsigned long long m23 = v0[2] < v0[3] ? v0[2] : v0[3];
            m = m23 < m ? m23 : m;
#pragma unroll
            for (int off = 1; off < 64; off <<= 1) {
                unsigned long long o = __shfl_xor(m, off);
                m = o < m ? o : m;
            }
            if (lane == 0) L1[cb + t] = m;
            bool owned = false;
#pragma unroll
            for (int q = 0; q < 4; ++q) {
                if (!owned && v0[q] == m) { v0[q] = ~0ull; owned = true; }
            }
        }
    }
    __syncthreads();
    if (tid < 32) {
        unsigned long long w = L1[tid];
        kidx[node * KNN + tid] = (int)(unsigned)(w & 0xffffffffull);
        kdist[node * KNN + tid] = __uint_as_float((unsigned)(w >> 32));
    }
}

// ---------------- edge kernel: combine(bf16) -> P tile -> MFMA layer2 ----------------
__global__ __launch_bounds__(256) void edge_kernel(
    const unsigned short* __restrict__ ABbf, const float* __restrict__ w3buf,
    const unsigned short* __restrict__ W2f, const float* __restrict__ be2,
    const unsigned short* __restrict__ hbf,
    const int* __restrict__ kidx, const float* __restrict__ kdist,
    unsigned short* __restrict__ nodein)
{
    __shared__ unsigned short P[KNN * PS];
    __shared__ float sA[544];
    __shared__ float sw3[544];
    __shared__ float accbuf[4][64][4];
    __shared__ int   kjs[KNN];
    __shared__ float kds[KNN];

    int node = blockIdx.x;
    int bbase = (node >> 12) << 12;
    int tid = threadIdx.x;
    int wv = tid >> 6, lane = tid & 63;
    const unsigned short* Bb = ABbf + (size_t)NNODES * ABS;

    int tile = wv & 1;
    int kb0 = (wv < 2) ? 0 : 9;
    int nkb = (wv < 2) ? 9 : 8;
    short8 bfr[9];
#pragma unroll
    for (int q = 0; q < 9; ++q)
        if (q < nkb) bfr[q] = *(const short8*)&W2f[((kb0 + q) * 64 + lane) * 8];

    const unsigned short* Arow = ABbf + (size_t)node * ABS;
    for (int o = tid; o < 544; o += 256) {
        sA[o]  = (o < EH) ? bf2f(Arow[o]) : 0.0f;
        sw3[o] = (o < EH) ? w3buf[o] : 0.0f;
    }
    if (tid < KNN) {
        kjs[tid] = kidx[node * KNN + tid];
        kds[tid] = kdist[node * KNN + tid];
    }
    for (int idx = tid; idx < KNN * 16; idx += 256) {  // zero P cols 528..543
        int rr = idx >> 4, cc = idx & 15;
        P[rr * PS + 528 + cc] = 0;
    }
    if (tid < 128) nodein[(size_t)node * NDIN_P + tid] = hbf[(size_t)node * DD + tid];
    if (tid >= 144 && tid < 160) nodein[(size_t)node * NDIN_P + tid] = 0;
    __syncthreads();

    // combine: P[e][o] = bf16(gelu(A_i[o] + B_j[o] + w3[o]*d)), o in [0,528)
    {
        int e = tid >> 3, s = tid & 7;
        int jg = bbase + kjs[e];
        float dist = kds[e];
        const unsigned short* Bj = Bb + (size_t)jg * ABS;
        unsigned short* Pe = &P[e * PS];
#pragma unroll
        for (int it = 0; it < 9; ++it) {
            int ch = s + (it << 3);
            if (ch < 66) {
                u16x8 bvv = *(const u16x8*)(Bj + (ch << 3));
                const float* a = &sA[ch << 3];
                const float* w = &sw3[ch << 3];
                u16x8 g;
#pragma unroll
                for (int q = 0; q < 8; ++q) {
                    float v = a[q] + bf2f(bvv[q]) + w[q] * dist;
                    g[q] = bf16rne(fast_gelu(v));
                }
                *(u16x8*)(Pe + (ch << 3)) = g;
            }
        }
    }
    __syncthreads();

    f32x4 acc = {0.0f, 0.0f, 0.0f, 0.0f};
    {
        int row = tile * 16 + (lane & 15);
        const unsigned short* Pb = &P[row * PS + ((lane >> 4) << 3)];
#pragma unroll
        for (int q = 0; q < 9; ++q) {
            if (q < nkb) {
                short8 a = *(const short8*)&Pb[(kb0 + q) * 32];
                acc = __builtin_amdgcn_mfma_f32_16x16x32_bf16(a, bfr[q], acc, 0, 0, 0);
            }
        }
    }
#pragma unroll
    for (int i = 0; i < 4; ++i) accbuf[wv][lane][i] = acc[i];
    __syncthreads();

    if (wv == 0) {
        float bias = be2[lane & 15];
        float p = 0.0f;
#pragma unroll
        for (int t = 0; t < 2; ++t)
#pragma unroll
            for (int i = 0; i < 4; ++i) {
                float dv = accbuf[t][lane][i] + accbuf[t + 2][lane][i];
                p += fast_gelu(dv + bias);
            }
        p += __shfl_xor(p, 16);
        p += __shfl_xor(p, 32);
        if (lane < CF) nodein[(size_t)node * NDIN_P + DD + lane] = bf16rne(p);
    }
}

extern "C" void kernel_launch(void* const* d_in, const int* in_sizes, int n_in,
                              void* d_out, int out_size, void* d_ws, size_t ws_size,
                              hipStream_t stream) {
    const float* h   = (const float*)d_in[0];
    const float* x   = (const float*)d_in[1];
    const float* We1 = (const float*)d_in[2];
    const float* be1 = (const float*)d_in[3];
    const float* We2 = (const float*)d_in[4];
    const float* be2 = (const float*)d_in[5];
    const float* Wn1 = (const float*)d_in[6];
    const float* bn1 = (const float*)d_in[7];
    const float* Wn2 = (const float*)d_in[8];
    const float* bn2 = (const float*)d_in[9];
    float* out = (float*)d_out;

    char* ws = (char*)d_ws;
    size_t off = 0;
    auto alloc = [&](size_t bytes) -> void* {
        void* p = ws + off;
        off = (off + bytes + 255) & ~(size_t)255;
        return p;
    };
    unsigned short* Wcatbf = (unsigned short*)alloc((size_t)NPAD * DD * 2);
    float* biascat = (float*)alloc((size_t)NPAD * 4);
    float* w3buf   = (float*)alloc((size_t)EH * 4);
    unsigned short* W2f   = (unsigned short*)alloc((size_t)NKB * 64 * 8 * 2);
    unsigned short* Wn1bf = (unsigned short*)alloc((size_t)NDH * NDIN_P * 2);
    unsigned short* Wn2bf = (unsigned short*)alloc((size_t)DD * NDH * 2);
    unsigned short* hbf   = (unsigned short*)alloc((size_t)NNODES * DD * 2);
    unsigned short* ABbf  = (unsigned short*)alloc((size_t)2 * NNODES * ABS * 2);
    int*   kidx   = (int*)alloc((size_t)NNODES * KNN * 4);
    float* kdist  = (float*)alloc((size_t)NNODES * KNN * 4);
    unsigned short* nodein = (unsigned short*)alloc((size_t)NNODES * NDIN_P * 2);
    unsigned short* hidbf  = (unsigned short*)alloc((size_t)NNODES * NDH * 2);

    // 1. repack weights (bf16)
    repack_kernel<<<NPAD * DD / 256, 256, 0, stream>>>(
        We1, be1, We2, Wn1, Wn2, Wcatbf, biascat, w3buf, W2f, Wn1bf, Wn2bf);
    // 2. h -> bf16
    hcast_kernel<<<NNODES * DD / 1024, 256, 0, stream>>>(h, hbf);
    // 3. KNN (radix select)
    knn_kernel<<<NNODES, 256, 0, stream>>>(x, kidx, kdist);
    // 4. AB = h @ Wcat^T + biascat -> split bf16 halves
    mgemm_kernel<0, 0, 1, 0, 2><<<dim3(NNODES / 128, NPAD / 64), 256, 0, stream>>>(
        hbf, DD, Wcatbf, DD, biascat, nullptr, 0, nullptr, 0, ABbf, EH2, DD / 32);
    // 5. edge MLP + aggregate -> nodein (bf16, stride 160)
    edge_kernel<<<NNODES, 256, 0, stream>>>(ABbf, w3buf, W2f, be2, hbf, kidx, kdist, nodein);
    // 6. hid = gelu(nodein @ Wn1^T + bn1) -> bf16
    mgemm_kernel<1, 0, 0, 1, 1><<<dim3(NNODES / 64, NDH / 64), 256, 0, stream>>>(
        nodein, NDIN_P, Wn1bf, NDIN_P, bn1, nullptr, 0, hidbf, NDH, nullptr, NDH, NDIN_P / 32);
    // 7. out = hid @ Wn2^T + bn2 + h (f32)
    mgemm_kernel<0, 1, 0, 0, 1><<<dim3(NNODES / 64, DD / 64), 256, 0, stream>>>(
        hidbf, NDH, Wn2bf, NDH, bn2, h, DD, out, DD, nullptr, DD, NDH / 32);
}